// Round 4
// baseline (284.975 us; speedup 1.0000x reference)
//
#include <hip/hip_runtime.h>

#define AS1 __attribute__((address_space(1)))
#define AS3 __attribute__((address_space(3)))

using bf16x8  = __attribute__((ext_vector_type(8))) __bf16;
using floatx4 = __attribute__((ext_vector_type(4))) float;

#define SCQ 0.18033688f   // (1/sqrt(64)) * log2(e), folded into Q weights/bias

__device__ inline ushort f2b(float f) {
    __bf16 h = (__bf16)f;
    return __builtin_bit_cast(ushort, h);
}

// ---------------- f32 -> bf16 flat convert ----------------
__global__ void k_conv(const float* __restrict__ in, ushort* __restrict__ out, int n) {
    int i = (blockIdx.x * 256 + threadIdx.x) * 4;
    if (i < n) {
        float4 v = *(const float4*)(in + i);
        ushort4 o;
        o.x = f2b(v.x); o.y = f2b(v.y); o.z = f2b(v.z); o.w = f2b(v.w);
        *(ushort4*)(out + i) = o;
    }
}

// ---- transpose + convert: out[n][r] = bf16(in[r][n] * (n < scale_cols ? scale : 1)) ----
__global__ void k_transpose(const float* __restrict__ in, ushort* __restrict__ out,
                            int R, int Ncol, float scale, int scale_cols) {
    __shared__ float tile[32][33];
    int tx = threadIdx.x & 31, ty = threadIdx.x >> 5;   // 32 x 8
    int c0 = blockIdx.x * 32, r0 = blockIdx.y * 32;
    for (int i = 0; i < 32; i += 8)
        tile[ty + i][tx] = in[(size_t)(r0 + ty + i) * Ncol + c0 + tx];
    __syncthreads();
    for (int i = 0; i < 32; i += 8) {
        int n = c0 + ty + i;
        float v = tile[tx][ty + i];
        if (n < scale_cols) v *= scale;
        out[(size_t)n * R + r0 + tx] = f2b(v);
    }
}

// ---------------- generic m97-style GEMM (proj): C[M,N] = A * Bt^T + bias, f32 out ----------------
__global__ __launch_bounds__(256, 2) void k_gemm_bt(
    const ushort* __restrict__ A, const ushort* __restrict__ Bt,
    const float* __restrict__ bias, float* __restrict__ outv,
    int M, int N, int K)
{
    __shared__ __align__(16) ushort As[128 * 32];
    __shared__ __align__(16) ushort Bs[128 * 32];
    int tid = threadIdx.x;
    int m0 = blockIdx.y * 128, n0 = blockIdx.x * 128;
    int lane = tid & 63;
    int wm = (tid >> 7) * 64;
    int wn = ((tid >> 6) & 1) * 64;
    int lr = lane & 15, quad = lane >> 4, lk = quad * 8;

    floatx4 acc[4][4] = {};
    const ushort* ag = A  + (size_t)(m0 + (tid >> 2)) * K + (tid & 3) * 8;
    const ushort* bg = Bt + (size_t)(n0 + (tid >> 2)) * K + (tid & 3) * 8;
    ushort* asd = &As[tid * 8];
    ushort* bsd = &Bs[tid * 8];

    for (int kt = 0; kt < K; kt += 32) {
        __builtin_amdgcn_global_load_lds((const AS1 unsigned int*)(ag + kt),                  (AS3 unsigned int*)(asd),        16, 0, 0);
        __builtin_amdgcn_global_load_lds((const AS1 unsigned int*)(ag + kt + (size_t)64 * K), (AS3 unsigned int*)(asd + 2048), 16, 0, 0);
        __builtin_amdgcn_global_load_lds((const AS1 unsigned int*)(bg + kt),                  (AS3 unsigned int*)(bsd),        16, 0, 0);
        __builtin_amdgcn_global_load_lds((const AS1 unsigned int*)(bg + kt + (size_t)64 * K), (AS3 unsigned int*)(bsd + 2048), 16, 0, 0);
        asm volatile("s_waitcnt vmcnt(0)" ::: "memory");
        __syncthreads();
        bf16x8 af[4], bf[4];
        #pragma unroll
        for (int i = 0; i < 4; ++i) af[i] = *(const bf16x8*)&As[(wm + 16 * i + lr) * 32 + lk];
        #pragma unroll
        for (int j = 0; j < 4; ++j) bf[j] = *(const bf16x8*)&Bs[(wn + 16 * j + lr) * 32 + lk];
        #pragma unroll
        for (int i = 0; i < 4; ++i)
            #pragma unroll
            for (int j = 0; j < 4; ++j)
                acc[i][j] = __builtin_amdgcn_mfma_f32_16x16x32_bf16(af[i], bf[j], acc[i][j], 0, 0, 0);
        __syncthreads();
    }

    #pragma unroll
    for (int j = 0; j < 4; ++j) {
        int col = n0 + wn + 16 * j + lr;
        float bv = bias[col];
        #pragma unroll
        for (int i = 0; i < 4; ++i) {
            int row = m0 + wm + 16 * i + quad * 4;
            #pragma unroll
            for (int r = 0; r < 4; ++r)
                outv[(size_t)(row + r) * N + col] = acc[i][j][r] + bv;
        }
    }
}

// ---------------- QKV GEMM: M=8192, N=3072, K=1024 ----------------
// Q/K columns (0..2047) -> qkv[row][col], row stride 2048 (Q pre-scaled by SCQ via weights).
// V columns (2048..3071) -> vt[((b*16+h)*64+d)*2048 + t]  (pre-transposed for attention).
__global__ __launch_bounds__(256, 2) void k_gemm_qkv(
    const ushort* __restrict__ A, const ushort* __restrict__ Bt,
    const float* __restrict__ bias, ushort* __restrict__ qkv, ushort* __restrict__ vt)
{
    constexpr int K = 1024;
    __shared__ __align__(16) ushort As[128 * 32];
    __shared__ __align__(16) ushort Bs[128 * 32];
    int tid = threadIdx.x;
    int m0 = blockIdx.y * 128, n0 = blockIdx.x * 128;
    int lane = tid & 63;
    int wm = (tid >> 7) * 64;
    int wn = ((tid >> 6) & 1) * 64;
    int lr = lane & 15, quad = lane >> 4, lk = quad * 8;

    floatx4 acc[4][4] = {};
    const ushort* ag = A  + (size_t)(m0 + (tid >> 2)) * K + (tid & 3) * 8;
    const ushort* bg = Bt + (size_t)(n0 + (tid >> 2)) * K + (tid & 3) * 8;
    ushort* asd = &As[tid * 8];
    ushort* bsd = &Bs[tid * 8];

    for (int kt = 0; kt < K; kt += 32) {
        __builtin_amdgcn_global_load_lds((const AS1 unsigned int*)(ag + kt),                  (AS3 unsigned int*)(asd),        16, 0, 0);
        __builtin_amdgcn_global_load_lds((const AS1 unsigned int*)(ag + kt + (size_t)64 * K), (AS3 unsigned int*)(asd + 2048), 16, 0, 0);
        __builtin_amdgcn_global_load_lds((const AS1 unsigned int*)(bg + kt),                  (AS3 unsigned int*)(bsd),        16, 0, 0);
        __builtin_amdgcn_global_load_lds((const AS1 unsigned int*)(bg + kt + (size_t)64 * K), (AS3 unsigned int*)(bsd + 2048), 16, 0, 0);
        asm volatile("s_waitcnt vmcnt(0)" ::: "memory");
        __syncthreads();
        bf16x8 af[4], bf[4];
        #pragma unroll
        for (int i = 0; i < 4; ++i) af[i] = *(const bf16x8*)&As[(wm + 16 * i + lr) * 32 + lk];
        #pragma unroll
        for (int j = 0; j < 4; ++j) bf[j] = *(const bf16x8*)&Bs[(wn + 16 * j + lr) * 32 + lk];
        #pragma unroll
        for (int i = 0; i < 4; ++i)
            #pragma unroll
            for (int j = 0; j < 4; ++j)
                acc[i][j] = __builtin_amdgcn_mfma_f32_16x16x32_bf16(af[i], bf[j], acc[i][j], 0, 0, 0);
        __syncthreads();
    }

    int bb = m0 >> 11;   // batch index (blocks are 128-row, T=2048-aligned)
    #pragma unroll
    for (int j = 0; j < 4; ++j) {
        int col = n0 + wn + 16 * j + lr;
        float bv = bias[col];
        if (col < 1024) bv *= SCQ;
        if (col < 2048) {
            #pragma unroll
            for (int i = 0; i < 4; ++i) {
                int row = m0 + wm + 16 * i + quad * 4;
                #pragma unroll
                for (int r = 0; r < 4; ++r)
                    qkv[(size_t)(row + r) * 2048 + col] = f2b(acc[i][j][r] + bv);
            }
        } else {
            int h = (col - 2048) >> 6, d = (col - 2048) & 63;
            ushort* vbase = vt + ((size_t)(bb * 16 + h) * 64 + d) * 2048;
            #pragma unroll
            for (int i = 0; i < 4; ++i) {
                int t0 = (m0 + wm + 16 * i + quad * 4) & 2047;
                ushort4 pk;
                ((ushort*)&pk)[0] = f2b(acc[i][j][0] + bv);
                ((ushort*)&pk)[1] = f2b(acc[i][j][1] + bv);
                ((ushort*)&pk)[2] = f2b(acc[i][j][2] + bv);
                ((ushort*)&pk)[3] = f2b(acc[i][j][3] + bv);
                *(ushort4*)&vbase[t0] = pk;
            }
        }
    }
}

// ---------------- causal flash attention, round 4 ----------------
// S^T formulation: S^T = K·Q^T (A=K-frag, B=Q-frag-as-B). C-layout of S^T gives each
// lane 4 CONSECUTIVE keys at fixed q -> P written as packed ds_write_b64 (was 16x b16).
// 32 q-rows/wave (2 q-sets), 128-key tiles (17 iters/block, uniform via {i,15-i} pairing).
// Row sums via ones-MFMA (lands in the PV-output lanes directly).
// grid (8, B*H); block 256 = 4 waves. LDS 67.6 KB -> 2 blocks/CU.
__global__ __launch_bounds__(256, 2) void k_attn(const ushort* __restrict__ qkv,
                                                 const ushort* __restrict__ vt,
                                                 ushort* __restrict__ out)
{
    constexpr int T = 2048, SQK = 2048, C = 1024;
    constexpr int PSTR = 136;                          // P row stride (128 keys + pad)
    __shared__ __align__(16) ushort Ks[128 * 64];      // [key][swizzled d-chunk]
    __shared__ __align__(16) ushort Vs[64 * 128];      // [dim][swizzled key-chunk]
    __shared__ __align__(16) ushort Ps[4 * 32 * PSTR]; // per-wave P, [q 32][key 128]
    int tid = threadIdx.x;
    int lane = tid & 63, wave = tid >> 6;
    int lr = lane & 15, quad = lane >> 4;
    int bh = blockIdx.y;
    int b = bh >> 4, h = bh & 15;
    size_t base = (size_t)b * T * SQK;
    const ushort* kg0 = qkv + base + 1024 + h * 64;
    const ushort* vg0 = vt + (size_t)bh * 64 * 2048;
    ushort* psw = &Ps[wave * 32 * PSTR];

    bf16x8 ones;
    #pragma unroll
    for (int i = 0; i < 8; ++i) ones[i] = (__bf16)1.0f;

    // K staging: 4 slots/thread; slot s covers (key = slot>>3, phys chunk = slot&7),
    // source chunk g = (slot&7) ^ (key&7).  V: slot -> (dim = slot>>4, phys = slot&15),
    // g = phys ^ (dim&15).
    int kslot[4], vslot[4];
    #pragma unroll
    for (int it = 0; it < 4; ++it) { kslot[it] = tid + 256 * it; vslot[it] = tid + 256 * it; }

    int qts[2] = { (int)blockIdx.x, 15 - (int)blockIdx.x };
    for (int ti = 0; ti < 2; ++ti) {
        int qt = qts[ti];
        int qrowW = qt * 128 + wave * 32;              // wave's first q row
        const ushort* qp0 = qkv + base + (size_t)(qrowW + lr) * SQK + h * 64;
        const ushort* qp1 = qkv + base + (size_t)(qrowW + 16 + lr) * SQK + h * 64;
        bf16x8 aq00 = *(const bf16x8*)(qp0 + quad * 8);
        bf16x8 aq01 = *(const bf16x8*)(qp0 + 32 + quad * 8);
        bf16x8 aq10 = *(const bf16x8*)(qp1 + quad * 8);
        bf16x8 aq11 = *(const bf16x8*)(qp1 + 32 + quad * 8);
        floatx4 o[2][4] = {};
        floatx4 lacc[2] = {};

        for (int kt = 0; kt <= qt; ++kt) {
            __syncthreads();
            #pragma unroll
            for (int it = 0; it < 4; ++it) {
                int sl = kslot[it];
                int key = sl >> 3, g = (sl & 7) ^ (key & 7);
                __builtin_amdgcn_global_load_lds(
                    (const AS1 unsigned int*)(kg0 + (size_t)(kt * 128 + key) * SQK + g * 8),
                    (AS3 unsigned int*)&Ks[sl * 8], 16, 0, 0);
            }
            #pragma unroll
            for (int it = 0; it < 4; ++it) {
                int sl = vslot[it];
                int dim = sl >> 4, g = (sl & 15) ^ (dim & 15);
                __builtin_amdgcn_global_load_lds(
                    (const AS1 unsigned int*)(vg0 + (size_t)dim * 2048 + kt * 128 + g * 8),
                    (AS3 unsigned int*)&Vs[sl * 8], 16, 0, 0);
            }
            asm volatile("s_waitcnt vmcnt(0)" ::: "memory");
            __syncthreads();

            bool diag = (kt == qt);
            // --- S^T = K Q^T, per 16-key m-tile; exp2 + packed b64 P write ---
            #pragma unroll
            for (int jk = 0; jk < 8; ++jk) {
                const ushort* kr = &Ks[(16 * jk + lr) * 64];
                bf16x8 ak0 = *(const bf16x8*)(kr + ((quad) ^ (lr & 7)) * 8);
                bf16x8 ak1 = *(const bf16x8*)(kr + ((4 + quad) ^ (lr & 7)) * 8);
                floatx4 z = {};
                floatx4 st0 = __builtin_amdgcn_mfma_f32_16x16x32_bf16(ak0, aq00, z, 0, 0, 0);
                st0 = __builtin_amdgcn_mfma_f32_16x16x32_bf16(ak1, aq01, st0, 0, 0, 0);
                floatx4 st1 = __builtin_amdgcn_mfma_f32_16x16x32_bf16(ak0, aq10, z, 0, 0, 0);
                st1 = __builtin_amdgcn_mfma_f32_16x16x32_bf16(ak1, aq11, st1, 0, 0, 0);
                int kloc = 16 * jk + quad * 4;
                if (diag) {
                    int q0l = wave * 32 + lr;
                    float p00 = (kloc + 0 > q0l) ? 0.f : exp2f(st0[0]);
                    float p01 = (kloc + 1 > q0l) ? 0.f : exp2f(st0[1]);
                    float p02 = (kloc + 2 > q0l) ? 0.f : exp2f(st0[2]);
                    float p03 = (kloc + 3 > q0l) ? 0.f : exp2f(st0[3]);
                    int q1l = q0l + 16;
                    float p10 = (kloc + 0 > q1l) ? 0.f : exp2f(st1[0]);
                    float p11 = (kloc + 1 > q1l) ? 0.f : exp2f(st1[1]);
                    float p12 = (kloc + 2 > q1l) ? 0.f : exp2f(st1[2]);
                    float p13 = (kloc + 3 > q1l) ? 0.f : exp2f(st1[3]);
                    uint2 w0, w1;
                    w0.x = (unsigned)f2b(p00) | ((unsigned)f2b(p01) << 16);
                    w0.y = (unsigned)f2b(p02) | ((unsigned)f2b(p03) << 16);
                    w1.x = (unsigned)f2b(p10) | ((unsigned)f2b(p11) << 16);
                    w1.y = (unsigned)f2b(p12) | ((unsigned)f2b(p13) << 16);
                    *(uint2*)&psw[(lr) * PSTR + kloc]      = w0;
                    *(uint2*)&psw[(16 + lr) * PSTR + kloc] = w1;
                } else {
                    uint2 w0, w1;
                    w0.x = (unsigned)f2b(exp2f(st0[0])) | ((unsigned)f2b(exp2f(st0[1])) << 16);
                    w0.y = (unsigned)f2b(exp2f(st0[2])) | ((unsigned)f2b(exp2f(st0[3])) << 16);
                    w1.x = (unsigned)f2b(exp2f(st1[0])) | ((unsigned)f2b(exp2f(st1[1])) << 16);
                    w1.y = (unsigned)f2b(exp2f(st1[2])) | ((unsigned)f2b(exp2f(st1[3])) << 16);
                    *(uint2*)&psw[(lr) * PSTR + kloc]      = w0;
                    *(uint2*)&psw[(16 + lr) * PSTR + kloc] = w1;
                }
            }
            asm volatile("s_waitcnt lgkmcnt(0)" ::: "memory");
            // --- P A-frags (b128, natural layout) + ones-MFMA row sums ---
            bf16x8 ap[2][4];
            #pragma unroll
            for (int t = 0; t < 2; ++t)
                #pragma unroll
                for (int s = 0; s < 4; ++s) {
                    ap[t][s] = *(const bf16x8*)&psw[(t * 16 + lr) * PSTR + s * 32 + quad * 8];
                    lacc[t] = __builtin_amdgcn_mfma_f32_16x16x32_bf16(ap[t][s], ones, lacc[t], 0, 0, 0);
                }
            // --- O += P V ---
            #pragma unroll
            for (int jd = 0; jd < 4; ++jd) {
                const ushort* vr = &Vs[(16 * jd + lr) * 128];
                #pragma unroll
                for (int s = 0; s < 4; ++s) {
                    bf16x8 bv = *(const bf16x8*)(vr + ((4 * s + quad) ^ lr) * 8);
                    o[0][jd] = __builtin_amdgcn_mfma_f32_16x16x32_bf16(ap[0][s], bv, o[0][jd], 0, 0, 0);
                    o[1][jd] = __builtin_amdgcn_mfma_f32_16x16x32_bf16(ap[1][s], bv, o[1][jd], 0, 0, 0);
                }
            }
        }

        #pragma unroll
        for (int t = 0; t < 2; ++t)
            #pragma unroll
            for (int r = 0; r < 4; ++r) {
                float inv = 1.0f / lacc[t][r];
                int row = b * T + qrowW + t * 16 + quad * 4 + r;
                #pragma unroll
                for (int jd = 0; jd < 4; ++jd)
                    out[(size_t)row * C + h * 64 + 16 * jd + lr] = f2b(o[t][jd][r] * inv);
            }
    }
}

extern "C" void kernel_launch(void* const* d_in, const int* in_sizes, int n_in,
                              void* d_out, int out_size, void* d_ws, size_t ws_size,
                              hipStream_t stream) {
    const float* x      = (const float*)d_in[0];
    const float* w_attn = (const float*)d_in[1];
    const float* b_attn = (const float*)d_in[2];
    const float* w_proj = (const float*)d_in[3];
    const float* b_proj = (const float*)d_in[4];
    float* out = (float*)d_out;

    constexpr int Bb = 4, T = 2048, C = 1024;
    constexpr int M = Bb * T;   // 8192

    // workspace layout (bf16 elements): ~92 MB total
    ushort* xb  = (ushort*)d_ws;                    // M*C
    ushort* waT = xb  + (size_t)M * C;              // 3C x C
    ushort* wpT = waT + (size_t)3 * C * C;          // C x C
    ushort* qkv = wpT + (size_t)C * C;              // M x 2C  (Q|K only)
    ushort* vt  = qkv + (size_t)M * 2 * C;          // 64 bh x 64 d x T (V^T)
    ushort* ao  = vt  + (size_t)64 * 64 * T;        // M x C

    k_conv<<<(M * C / 4 + 255) / 256, 256, 0, stream>>>(x, xb, M * C);
    k_transpose<<<dim3(3 * C / 32, C / 32), 256, 0, stream>>>(w_attn, waT, C, 3 * C, SCQ, C);
    k_transpose<<<dim3(C / 32, C / 32), 256, 0, stream>>>(w_proj, wpT, C, C, 1.0f, 0);
    k_gemm_qkv<<<dim3(3 * C / 128, M / 128), 256, 0, stream>>>(xb, waT, b_attn, qkv, vt);
    k_attn<<<dim3(8, Bb * 16), 256, 0, stream>>>(qkv, vt, ao);
    k_gemm_bt<<<dim3(C / 128, M / 128), 256, 0, stream>>>(ao, wpT, b_proj, out, M, C, C);
}

// Round 5
// 267.748 us; speedup vs baseline: 1.0643x; 1.0643x over previous
//
#include <hip/hip_runtime.h>

#define AS1 __attribute__((address_space(1)))
#define AS3 __attribute__((address_space(3)))

using bf16x8  = __attribute__((ext_vector_type(8))) __bf16;
using floatx4 = __attribute__((ext_vector_type(4))) float;

#define SCQ 0.18033688f   // (1/sqrt(64)) * log2(e), folded into Q weights/bias

__device__ inline ushort f2b(float f) {
    __bf16 h = (__bf16)f;
    return __builtin_bit_cast(ushort, h);
}

// ---------------- f32 -> bf16 flat convert ----------------
__global__ void k_conv(const float* __restrict__ in, ushort* __restrict__ out, int n) {
    int i = (blockIdx.x * 256 + threadIdx.x) * 4;
    if (i < n) {
        float4 v = *(const float4*)(in + i);
        ushort4 o;
        o.x = f2b(v.x); o.y = f2b(v.y); o.z = f2b(v.z); o.w = f2b(v.w);
        *(ushort4*)(out + i) = o;
    }
}

// ---- transpose + convert: out[n][r] = bf16(in[r][n] * (n < scale_cols ? scale : 1)) ----
__global__ void k_transpose(const float* __restrict__ in, ushort* __restrict__ out,
                            int R, int Ncol, float scale, int scale_cols) {
    __shared__ float tile[32][33];
    int tx = threadIdx.x & 31, ty = threadIdx.x >> 5;   // 32 x 8
    int c0 = blockIdx.x * 32, r0 = blockIdx.y * 32;
    for (int i = 0; i < 32; i += 8)
        tile[ty + i][tx] = in[(size_t)(r0 + ty + i) * Ncol + c0 + tx];
    __syncthreads();
    for (int i = 0; i < 32; i += 8) {
        int n = c0 + ty + i;
        float v = tile[tx][ty + i];
        if (n < scale_cols) v *= scale;
        out[(size_t)n * R + r0 + tx] = f2b(v);
    }
}

// ---------------- generic m97-style GEMM (proj): C[M,N] = A * Bt^T + bias, f32 out ----------------
__global__ __launch_bounds__(256, 2) void k_gemm_bt(
    const ushort* __restrict__ A, const ushort* __restrict__ Bt,
    const float* __restrict__ bias, float* __restrict__ outv,
    int M, int N, int K)
{
    __shared__ __align__(16) ushort As[128 * 32];
    __shared__ __align__(16) ushort Bs[128 * 32];
    int tid = threadIdx.x;
    int m0 = blockIdx.y * 128, n0 = blockIdx.x * 128;
    int lane = tid & 63;
    int wm = (tid >> 7) * 64;
    int wn = ((tid >> 6) & 1) * 64;
    int lr = lane & 15, quad = lane >> 4, lk = quad * 8;

    floatx4 acc[4][4] = {};
    const ushort* ag = A  + (size_t)(m0 + (tid >> 2)) * K + (tid & 3) * 8;
    const ushort* bg = Bt + (size_t)(n0 + (tid >> 2)) * K + (tid & 3) * 8;
    ushort* asd = &As[tid * 8];
    ushort* bsd = &Bs[tid * 8];

    for (int kt = 0; kt < K; kt += 32) {
        __builtin_amdgcn_global_load_lds((const AS1 unsigned int*)(ag + kt),                  (AS3 unsigned int*)(asd),        16, 0, 0);
        __builtin_amdgcn_global_load_lds((const AS1 unsigned int*)(ag + kt + (size_t)64 * K), (AS3 unsigned int*)(asd + 2048), 16, 0, 0);
        __builtin_amdgcn_global_load_lds((const AS1 unsigned int*)(bg + kt),                  (AS3 unsigned int*)(bsd),        16, 0, 0);
        __builtin_amdgcn_global_load_lds((const AS1 unsigned int*)(bg + kt + (size_t)64 * K), (AS3 unsigned int*)(bsd + 2048), 16, 0, 0);
        asm volatile("s_waitcnt vmcnt(0)" ::: "memory");
        __syncthreads();
        bf16x8 af[4], bf[4];
        #pragma unroll
        for (int i = 0; i < 4; ++i) af[i] = *(const bf16x8*)&As[(wm + 16 * i + lr) * 32 + lk];
        #pragma unroll
        for (int j = 0; j < 4; ++j) bf[j] = *(const bf16x8*)&Bs[(wn + 16 * j + lr) * 32 + lk];
        #pragma unroll
        for (int i = 0; i < 4; ++i)
            #pragma unroll
            for (int j = 0; j < 4; ++j)
                acc[i][j] = __builtin_amdgcn_mfma_f32_16x16x32_bf16(af[i], bf[j], acc[i][j], 0, 0, 0);
        __syncthreads();
    }

    #pragma unroll
    for (int j = 0; j < 4; ++j) {
        int col = n0 + wn + 16 * j + lr;
        float bv = bias[col];
        #pragma unroll
        for (int i = 0; i < 4; ++i) {
            int row = m0 + wm + 16 * i + quad * 4;
            #pragma unroll
            for (int r = 0; r < 4; ++r)
                outv[(size_t)(row + r) * N + col] = acc[i][j][r] + bv;
        }
    }
}

// ---------------- QKV GEMM: M=8192, N=3072, K=1024 ----------------
// Q/K columns (0..2047) -> qkv[row][col], row stride 2048 (Q pre-scaled by SCQ via weights).
// V columns (2048..3071) -> vt[((b*16+h)*64+d)*2048 + t]  (pre-transposed for attention).
__global__ __launch_bounds__(256, 2) void k_gemm_qkv(
    const ushort* __restrict__ A, const ushort* __restrict__ Bt,
    const float* __restrict__ bias, ushort* __restrict__ qkv, ushort* __restrict__ vt)
{
    constexpr int K = 1024;
    __shared__ __align__(16) ushort As[128 * 32];
    __shared__ __align__(16) ushort Bs[128 * 32];
    int tid = threadIdx.x;
    int m0 = blockIdx.y * 128, n0 = blockIdx.x * 128;
    int lane = tid & 63;
    int wm = (tid >> 7) * 64;
    int wn = ((tid >> 6) & 1) * 64;
    int lr = lane & 15, quad = lane >> 4, lk = quad * 8;

    floatx4 acc[4][4] = {};
    const ushort* ag = A  + (size_t)(m0 + (tid >> 2)) * K + (tid & 3) * 8;
    const ushort* bg = Bt + (size_t)(n0 + (tid >> 2)) * K + (tid & 3) * 8;
    ushort* asd = &As[tid * 8];
    ushort* bsd = &Bs[tid * 8];

    for (int kt = 0; kt < K; kt += 32) {
        __builtin_amdgcn_global_load_lds((const AS1 unsigned int*)(ag + kt),                  (AS3 unsigned int*)(asd),        16, 0, 0);
        __builtin_amdgcn_global_load_lds((const AS1 unsigned int*)(ag + kt + (size_t)64 * K), (AS3 unsigned int*)(asd + 2048), 16, 0, 0);
        __builtin_amdgcn_global_load_lds((const AS1 unsigned int*)(bg + kt),                  (AS3 unsigned int*)(bsd),        16, 0, 0);
        __builtin_amdgcn_global_load_lds((const AS1 unsigned int*)(bg + kt + (size_t)64 * K), (AS3 unsigned int*)(bsd + 2048), 16, 0, 0);
        asm volatile("s_waitcnt vmcnt(0)" ::: "memory");
        __syncthreads();
        bf16x8 af[4], bf[4];
        #pragma unroll
        for (int i = 0; i < 4; ++i) af[i] = *(const bf16x8*)&As[(wm + 16 * i + lr) * 32 + lk];
        #pragma unroll
        for (int j = 0; j < 4; ++j) bf[j] = *(const bf16x8*)&Bs[(wn + 16 * j + lr) * 32 + lk];
        #pragma unroll
        for (int i = 0; i < 4; ++i)
            #pragma unroll
            for (int j = 0; j < 4; ++j)
                acc[i][j] = __builtin_amdgcn_mfma_f32_16x16x32_bf16(af[i], bf[j], acc[i][j], 0, 0, 0);
        __syncthreads();
    }

    int bb = m0 >> 11;   // batch index (blocks are 128-row, T=2048-aligned)
    #pragma unroll
    for (int j = 0; j < 4; ++j) {
        int col = n0 + wn + 16 * j + lr;
        float bv = bias[col];
        if (col < 1024) bv *= SCQ;
        if (col < 2048) {
            #pragma unroll
            for (int i = 0; i < 4; ++i) {
                int row = m0 + wm + 16 * i + quad * 4;
                #pragma unroll
                for (int r = 0; r < 4; ++r)
                    qkv[(size_t)(row + r) * 2048 + col] = f2b(acc[i][j][r] + bv);
            }
        } else {
            int h = (col - 2048) >> 6, d = (col - 2048) & 63;
            ushort* vbase = vt + ((size_t)(bb * 16 + h) * 64 + d) * 2048;
            #pragma unroll
            for (int i = 0; i < 4; ++i) {
                int t0 = (m0 + wm + 16 * i + quad * 4) & 2047;
                ushort4 pk;
                ((ushort*)&pk)[0] = f2b(acc[i][j][0] + bv);
                ((ushort*)&pk)[1] = f2b(acc[i][j][1] + bv);
                ((ushort*)&pk)[2] = f2b(acc[i][j][2] + bv);
                ((ushort*)&pk)[3] = f2b(acc[i][j][3] + bv);
                *(ushort4*)&vbase[t0] = pk;
            }
        }
    }
}

// ---------------- causal flash attention, round 5 ----------------
// Round-3 shape (512 thr / 8 waves / 16 q-rows per wave / 64-key tiles / {i,15-i} pairing)
// + double-buffered K/V staging (prefetch tile kt+1 during compute of kt)
// + S^T = K*Q^T formulation: C-layout gives 4 consecutive keys/lane -> packed b64 P writes.
__global__ __launch_bounds__(512, 4) void k_attn(const ushort* __restrict__ qkv,
                                                 const ushort* __restrict__ vt,
                                                 ushort* __restrict__ out)
{
    constexpr int T = 2048, SQK = 2048, C = 1024;
    __shared__ __align__(16) ushort Ks[2 * 64 * 64];   // dbuf [key][swizzled d-chunk]
    __shared__ __align__(16) ushort Vs[2 * 64 * 64];   // dbuf [dim][swizzled key-chunk]
    __shared__ __align__(16) ushort Ps[8 * 16 * 72];   // per-wave P, [q][key], stride 72
    int tid = threadIdx.x;
    int lane = tid & 63, wave = tid >> 6;
    int lr = lane & 15, quad = lane >> 4, lk = quad * 8;
    int bh = blockIdx.y;
    int b = bh >> 4, h = bh & 15;
    size_t base = (size_t)b * T * SQK;
    const ushort* kg0 = qkv + base + 1024 + h * 64;
    const ushort* vg0 = vt + (size_t)bh * 64 * 2048;
    ushort* psw = &Ps[wave * 16 * 72];

    int srow = tid >> 3;                     // key (K) / dim (V)
    int sg   = (tid & 7) ^ (srow & 7);       // XOR-swizzled source chunk
    const ushort* kgs = kg0 + (size_t)srow * SQK + sg * 8;
    const ushort* vgs = vg0 + (size_t)srow * 2048 + sg * 8;

    bf16x8 ones;
    #pragma unroll
    for (int i = 0; i < 8; ++i) ones[i] = (__bf16)1.0f;
    int c0 = (quad ^ (lr & 7)) * 8;          // physical chunk for logical k 0..31
    int c1 = ((4 + quad) ^ (lr & 7)) * 8;    // physical chunk for logical k 32..63

    int qts[2] = { (int)blockIdx.x, 15 - (int)blockIdx.x };
    for (int ti = 0; ti < 2; ++ti) {
        int qt = qts[ti];
        int qrow = qt * 128 + wave * 16;
        int kt_d = qrow >> 6;                // this wave's diagonal tile
        int qoff = (qrow & 63) + lr;         // local q for diagonal masking
        const ushort* qp = qkv + base + (size_t)(qrow + lr) * SQK + h * 64;
        bf16x8 aq0 = *(const bf16x8*)(qp + lk);
        bf16x8 aq1 = *(const bf16x8*)(qp + 32 + lk);
        floatx4 o[4] = {};
        floatx4 lacc = {};
        int ktmax = 2 * qt + 1;

        __syncthreads();   // all waves done with buffers from previous q-tile
        // prefetch tile 0 -> buf 0
        __builtin_amdgcn_global_load_lds((const AS1 unsigned int*)(kgs),
                                         (AS3 unsigned int*)&Ks[tid * 8], 16, 0, 0);
        __builtin_amdgcn_global_load_lds((const AS1 unsigned int*)(vgs),
                                         (AS3 unsigned int*)&Vs[tid * 8], 16, 0, 0);

        for (int kt = 0; kt <= ktmax; ++kt) {
            int cur = kt & 1;
            asm volatile("s_waitcnt vmcnt(0)" ::: "memory");
            __syncthreads();
            if (kt < ktmax) {   // prefetch kt+1 into the other buffer
                int nb = cur ^ 1;
                __builtin_amdgcn_global_load_lds(
                    (const AS1 unsigned int*)(kgs + (size_t)(kt + 1) * 64 * SQK),
                    (AS3 unsigned int*)&Ks[nb * 4096 + tid * 8], 16, 0, 0);
                __builtin_amdgcn_global_load_lds(
                    (const AS1 unsigned int*)(vgs + (kt + 1) * 64),
                    (AS3 unsigned int*)&Vs[nb * 4096 + tid * 8], 16, 0, 0);
            }
            if (kt > kt_d) continue;
            const ushort* Kb = &Ks[cur * 4096];
            const ushort* Vb = &Vs[cur * 4096];
            bool diag = (kt == kt_d);

            // --- S^T = K Q^T per 16-key tile; exp2 + packed b64 P write ---
            #pragma unroll
            for (int jk = 0; jk < 4; ++jk) {
                const ushort* kr = &Kb[(16 * jk + lr) * 64];
                bf16x8 ak0 = *(const bf16x8*)(kr + c0);
                bf16x8 ak1 = *(const bf16x8*)(kr + c1);
                floatx4 z = {};
                floatx4 st = __builtin_amdgcn_mfma_f32_16x16x32_bf16(ak0, aq0, z, 0, 0, 0);
                st = __builtin_amdgcn_mfma_f32_16x16x32_bf16(ak1, aq1, st, 0, 0, 0);
                int kloc = 16 * jk + quad * 4;
                uint2 w;
                if (diag) {
                    float p0 = (kloc + 0 > qoff) ? 0.f : exp2f(st[0]);
                    float p1 = (kloc + 1 > qoff) ? 0.f : exp2f(st[1]);
                    float p2 = (kloc + 2 > qoff) ? 0.f : exp2f(st[2]);
                    float p3 = (kloc + 3 > qoff) ? 0.f : exp2f(st[3]);
                    w.x = (unsigned)f2b(p0) | ((unsigned)f2b(p1) << 16);
                    w.y = (unsigned)f2b(p2) | ((unsigned)f2b(p3) << 16);
                } else {
                    w.x = (unsigned)f2b(exp2f(st[0])) | ((unsigned)f2b(exp2f(st[1])) << 16);
                    w.y = (unsigned)f2b(exp2f(st[2])) | ((unsigned)f2b(exp2f(st[3])) << 16);
                }
                *(uint2*)&psw[lr * 72 + kloc] = w;
            }
            asm volatile("s_waitcnt lgkmcnt(0)" ::: "memory");
            bf16x8 ap0 = *(const bf16x8*)&psw[lr * 72 + lk];
            bf16x8 ap1 = *(const bf16x8*)&psw[lr * 72 + 32 + lk];
            // row sums on the matrix pipe
            lacc = __builtin_amdgcn_mfma_f32_16x16x32_bf16(ap0, ones, lacc, 0, 0, 0);
            lacc = __builtin_amdgcn_mfma_f32_16x16x32_bf16(ap1, ones, lacc, 0, 0, 0);
            // --- O += P V ---
            #pragma unroll
            for (int jd = 0; jd < 4; ++jd) {
                const ushort* vr = &Vb[(16 * jd + lr) * 64];
                bf16x8 bv0 = *(const bf16x8*)(vr + c0);
                bf16x8 bv1 = *(const bf16x8*)(vr + c1);
                o[jd] = __builtin_amdgcn_mfma_f32_16x16x32_bf16(ap0, bv0, o[jd], 0, 0, 0);
                o[jd] = __builtin_amdgcn_mfma_f32_16x16x32_bf16(ap1, bv1, o[jd], 0, 0, 0);
            }
        }

        #pragma unroll
        for (int r = 0; r < 4; ++r) {
            float inv = 1.0f / lacc[r];
            int row = b * T + qrow + quad * 4 + r;
            #pragma unroll
            for (int jd = 0; jd < 4; ++jd)
                out[(size_t)row * C + h * 64 + 16 * jd + lr] = f2b(o[jd][r] * inv);
        }
    }
}

extern "C" void kernel_launch(void* const* d_in, const int* in_sizes, int n_in,
                              void* d_out, int out_size, void* d_ws, size_t ws_size,
                              hipStream_t stream) {
    const float* x      = (const float*)d_in[0];
    const float* w_attn = (const float*)d_in[1];
    const float* b_attn = (const float*)d_in[2];
    const float* w_proj = (const float*)d_in[3];
    const float* b_proj = (const float*)d_in[4];
    float* out = (float*)d_out;

    constexpr int Bb = 4, T = 2048, C = 1024;
    constexpr int M = Bb * T;   // 8192

    // workspace layout (bf16 elements): ~92 MB total
    ushort* xb  = (ushort*)d_ws;                    // M*C
    ushort* waT = xb  + (size_t)M * C;              // 3C x C
    ushort* wpT = waT + (size_t)3 * C * C;          // C x C
    ushort* qkv = wpT + (size_t)C * C;              // M x 2C  (Q|K only)
    ushort* vt  = qkv + (size_t)M * 2 * C;          // 64 bh x 64 d x T (V^T)
    ushort* ao  = vt  + (size_t)64 * 64 * T;        // M x C

    k_conv<<<(M * C / 4 + 255) / 256, 256, 0, stream>>>(x, xb, M * C);
    k_transpose<<<dim3(3 * C / 32, C / 32), 256, 0, stream>>>(w_attn, waT, C, 3 * C, SCQ, C);
    k_transpose<<<dim3(C / 32, C / 32), 256, 0, stream>>>(w_proj, wpT, C, C, 1.0f, 0);
    k_gemm_qkv<<<dim3(3 * C / 128, M / 128), 256, 0, stream>>>(xb, waT, b_attn, qkv, vt);
    k_attn<<<dim3(8, Bb * 16), 512, 0, stream>>>(qkv, vt, ao);
    k_gemm_bt<<<dim3(C / 128, M / 128), 256, 0, stream>>>(ao, wpT, b_proj, out, M, C, C);
}